// Round 1
// baseline (205.212 us; speedup 1.0000x reference)
//
#include <hip/hip_runtime.h>

#define HW  262144     // 512*512
#define HW4 65536      // HW/4
#define NPATCH 16384   // 16 * 32 * 32

// ws layout (floats):
// [0]                : exposure sum of (patch_mean - E)^2
// [1]                : tv vertical sum
// [2]                : tv horizontal sum
// [3 .. 51)          : color channel sums, index 3 + b*3 + c   (48)
// [51 .. 51+128*11)  : semantic stats, index 51 + (b*8+k)*11 + s
//                      s: 0=sumM 1=sumM2 2..4=sRM[c] 5..7=sRM2[c] 8..10=sR2M2[c]
#define WS_FLOATS (3 + 48 + 128*11)

__device__ __forceinline__ float wave_reduce(float x) {
#pragma unroll
  for (int o = 32; o >= 1; o >>= 1) x += __shfl_down(x, o);
  return x;
}

// ---------------- semantic stats: R (B,3,H,W) x M (B,8,H,W) ----------------
__global__ __launch_bounds__(256) void sem_kernel(const float* __restrict__ R,
                                                  const float* __restrict__ M,
                                                  float* __restrict__ ws) {
  const int b  = blockIdx.y;
  const int tx = threadIdx.x;   // 0..63  (one full wave per ty row)
  const int ty = threadIdx.y;   // 0..3 -> k pair {2*ty, 2*ty+1}
  const int k0 = ty * 2;
  const float4* R4 = (const float4*)(R + (size_t)b * 3 * HW);
  const float4* M4 = (const float4*)(M + (size_t)b * 8 * HW);

  float sM[2]  = {0.f, 0.f};
  float sM2[2] = {0.f, 0.f};
  float sRM[2][3]   = {{0.f,0.f,0.f},{0.f,0.f,0.f}};
  float sRM2[2][3]  = {{0.f,0.f,0.f},{0.f,0.f,0.f}};
  float sR2M2[2][3] = {{0.f,0.f,0.f},{0.f,0.f,0.f}};

  for (int i = blockIdx.x * 64 + tx; i < HW4; i += gridDim.x * 64) {
    float4 r0 = R4[i];
    float4 r1 = R4[HW4 + i];
    float4 r2 = R4[2 * HW4 + i];
    float r[3][4] = {{r0.x, r0.y, r0.z, r0.w},
                     {r1.x, r1.y, r1.z, r1.w},
                     {r2.x, r2.y, r2.z, r2.w}};
#pragma unroll
    for (int kk = 0; kk < 2; ++kk) {
      float4 mv = M4[(k0 + kk) * HW4 + i];
      float m[4] = {mv.x, mv.y, mv.z, mv.w};
#pragma unroll
      for (int e = 0; e < 4; ++e) {
        float mm = m[e], mm2 = mm * mm;
        sM[kk]  += mm;
        sM2[kk] += mm2;
#pragma unroll
        for (int c = 0; c < 3; ++c) {
          float rr = r[c][e];
          sRM[kk][c]   += rr * mm;
          sRM2[kk][c]  += rr * mm2;
          sR2M2[kk][c] += rr * rr * mm2;
        }
      }
    }
  }

#pragma unroll
  for (int kk = 0; kk < 2; ++kk) {
    float st[11] = {sM[kk], sM2[kk],
                    sRM[kk][0],   sRM[kk][1],   sRM[kk][2],
                    sRM2[kk][0],  sRM2[kk][1],  sRM2[kk][2],
                    sR2M2[kk][0], sR2M2[kk][1], sR2M2[kk][2]};
    float* dst = ws + 51 + (size_t)((b * 8 + k0 + kk) * 11);
#pragma unroll
    for (int s = 0; s < 11; ++s) {
      float v = wave_reduce(st[s]);
      if (tx == 0) atomicAdd(&dst[s], v);
    }
  }
}

// ---------------- color: per (b,c) channel sums of I_enh ----------------
__global__ __launch_bounds__(256) void color_kernel(const float* __restrict__ I,
                                                    float* __restrict__ ws) {
  const int slice = blockIdx.y;  // b*3 + c, 0..47
  const float4* I4 = (const float4*)(I + (size_t)slice * HW);
  float s = 0.f;
  for (int i = blockIdx.x * blockDim.x + threadIdx.x; i < HW4;
       i += gridDim.x * blockDim.x) {
    float4 v = I4[i];
    s += (v.x + v.y) + (v.z + v.w);
  }
  s = wave_reduce(s);
  __shared__ float red[4];
  int wv = threadIdx.x >> 6, lane = threadIdx.x & 63;
  if (lane == 0) red[wv] = s;
  __syncthreads();
  if (threadIdx.x == 0)
    atomicAdd(&ws[3 + slice], (red[0] + red[1]) + (red[2] + red[3]));
}

// ---------------- total variation over L (B,1,H,W) ----------------
__global__ __launch_bounds__(256) void tv_kernel(const float* __restrict__ L,
                                                 float* __restrict__ ws) {
  const float4* L4 = (const float4*)L;
  const int NT4 = 16 * HW4;  // 1048576 float4s
  float sv = 0.f, sh = 0.f;
  for (int i = blockIdx.x * blockDim.x + threadIdx.x; i < NT4;
       i += gridDim.x * blockDim.x) {
    float4 v = L4[i];
    int p = i << 2;           // flat float index
    int w = p & 511;
    int h = (p >> 9) & 511;
    sh += fabsf(v.x - v.y) + fabsf(v.y - v.z) + fabsf(v.z - v.w);
    if (w != 508) sh += fabsf(v.w - L[p + 4]);
    if (h != 511) {
      float4 d = L4[i + 128];  // +512 floats = next row
      sv += fabsf(v.x - d.x) + fabsf(v.y - d.y) + fabsf(v.z - d.z) +
            fabsf(v.w - d.w);
    }
  }
  sv = wave_reduce(sv);
  sh = wave_reduce(sh);
  __shared__ float redv[4], redh[4];
  int wv = threadIdx.x >> 6, lane = threadIdx.x & 63;
  if (lane == 0) { redv[wv] = sv; redh[wv] = sh; }
  __syncthreads();
  if (threadIdx.x == 0) {
    atomicAdd(&ws[1], (redv[0] + redv[1]) + (redv[2] + redv[3]));
    atomicAdd(&ws[2], (redh[0] + redh[1]) + (redh[2] + redh[3]));
  }
}

// ---------------- exposure: 16x16 patch means of L ----------------
__global__ __launch_bounds__(256) void exp_kernel(const float* __restrict__ L,
                                                  float* __restrict__ ws) {
  int wv = threadIdx.x >> 6, lane = threadIdx.x & 63;
  int wave_global = blockIdx.x * 4 + wv;  // 0..4095
  float acc = 0.f;
#pragma unroll
  for (int j = 0; j < 4; ++j) {
    int patch = wave_global * 4 + j;      // 0..16383
    int b  = patch >> 10;
    int pr = (patch >> 5) & 31;
    int pc = patch & 31;
    const float* base = L + (size_t)b * HW + pr * (16 * 512) + pc * 16;
    int row = lane >> 2, c4 = lane & 3;
    float4 v = *(const float4*)(base + row * 512 + c4 * 4);
    float s = (v.x + v.y) + (v.z + v.w);
    s = wave_reduce(s);
    if (lane == 0) {
      float d = s * (1.0f / 256.0f) - 0.6f;
      acc += d * d;
    }
  }
  __shared__ float red[4];
  if (lane == 0) red[wv] = acc;
  __syncthreads();
  if (threadIdx.x == 0)
    atomicAdd(&ws[0], (red[0] + red[1]) + (red[2] + red[3]));
}

// ---------------- final combine ----------------
__global__ __launch_bounds__(256) void final_kernel(const float* __restrict__ ws,
                                                    float* __restrict__ out) {
  __shared__ float red[256];
  int t = threadIdx.x;
  float sem = 0.f;
  if (t < 128) {
    const float* s = ws + 51 + t * 11;
    float n = s[0] + 1e-6f;
    float v = 0.f;
#pragma unroll
    for (int c = 0; c < 3; ++c) {
      float mean = s[2 + c] / n;
      v += s[8 + c] - 2.0f * mean * s[5 + c] + mean * mean * s[1];
    }
    sem = v / n;
  }
  red[t] = sem;
  __syncthreads();
  for (int s = 128; s > 0; s >>= 1) {
    if (t < s) red[t] += red[t + s];
    __syncthreads();
  }
  if (t == 0) {
    float L_sem = red[0] / 16.0f;
    float L_exp = ws[0] / (float)NPATCH;
    float L_tv  = ws[1] / (16.0f * 511.0f * 512.0f) +
                  ws[2] / (16.0f * 512.0f * 511.0f);
    float L_color = 0.f;
#pragma unroll
    for (int b = 0; b < 16; ++b) {
      float r = ws[3 + b * 3 + 0] * (1.0f / (float)HW);
      float g = ws[3 + b * 3 + 1] * (1.0f / (float)HW);
      float bl = ws[3 + b * 3 + 2] * (1.0f / (float)HW);
      L_color += (r - g) * (r - g) + (r - bl) * (r - bl) + (g - bl) * (g - bl);
    }
    L_color *= (1.0f / 16.0f);
    out[0] = 10.0f * L_exp + 1.0f * L_tv + 10.0f * L_color + 50.0f * L_sem;
  }
}

extern "C" void kernel_launch(void* const* d_in, const int* in_sizes, int n_in,
                              void* d_out, int out_size, void* d_ws, size_t ws_size,
                              hipStream_t stream) {
  const float* L     = (const float*)d_in[0];  // (16,1,512,512)
  const float* R     = (const float*)d_in[1];  // (16,3,512,512)
  const float* I_enh = (const float*)d_in[2];  // (16,3,512,512)
  const float* M     = (const float*)d_in[3];  // (16,8,512,512)
  float* out = (float*)d_out;
  float* ws  = (float*)d_ws;

  hipMemsetAsync(d_ws, 0, WS_FLOATS * sizeof(float), stream);

  dim3 semBlock(64, 4, 1), semGrid(128, 16, 1);
  sem_kernel<<<semGrid, semBlock, 0, stream>>>(R, M, ws);

  dim3 colGrid(64, 48, 1);
  color_kernel<<<colGrid, 256, 0, stream>>>(I_enh, ws);

  tv_kernel<<<1024, 256, 0, stream>>>(L, ws);

  exp_kernel<<<1024, 256, 0, stream>>>(L, ws);

  final_kernel<<<1, 256, 0, stream>>>(ws, out);
}

// Round 2
// 128.551 us; speedup vs baseline: 1.5963x; 1.5963x over previous
//
#include <hip/hip_runtime.h>

#define HW  262144     // 512*512
#define HW4 65536      // HW/4
#define NPATCH 16384   // 16 * 32 * 32

// ws layout (floats):
// [0]                : exposure sum of (patch_mean - E)^2
// [1]                : tv vertical sum
// [2]                : tv horizontal sum
// [3 .. 51)          : color channel sums, index 3 + b*3 + c   (48)
// [51 .. 51+128*11)  : semantic stats, index 51 + (b*8+k)*11 + s
//                      s: 0=sumM 1=sumM2 2..4=sRM[c] 5..7=sRM2[c] 8..10=sR2M2[c]
#define WS_FLOATS (3 + 48 + 128*11)

#define SEM_BLOCKS   2048
#define L_BLOCKS     512
#define COLOR_BLOCKS 768
#define TOTAL_BLOCKS (SEM_BLOCKS + L_BLOCKS + COLOR_BLOCKS)

__device__ __forceinline__ float wave_reduce(float x) {
#pragma unroll
  for (int o = 32; o >= 1; o >>= 1) x += __shfl_down(x, o);
  return x;
}

// 11 named scalar accumulators per k — NO arrays, so nothing can demote to scratch.
// n=sumM, n2=sumM2, p*=sRM[c], q*=sRM2[c], r*=sR2M2[c]
#define SEM_ACC(P)                                                             \
  float P##n = 0.f, P##n2 = 0.f, P##p0 = 0.f, P##p1 = 0.f, P##p2 = 0.f,       \
        P##q0 = 0.f, P##q1 = 0.f, P##q2 = 0.f, P##r0 = 0.f, P##r1 = 0.f,      \
        P##r2 = 0.f;

#define SEM_DO(P, mm, x0, x1, x2)                                              \
  {                                                                            \
    float _m = (mm);                                                           \
    float _m2 = _m * _m;                                                       \
    P##n += _m;                                                                \
    P##n2 += _m2;                                                              \
    P##p0 += (x0) * _m;                                                        \
    P##p1 += (x1) * _m;                                                        \
    P##p2 += (x2) * _m;                                                        \
    P##q0 += (x0) * _m2;                                                       \
    P##q1 += (x1) * _m2;                                                       \
    P##q2 += (x2) * _m2;                                                       \
    P##r0 += (x0) * (x0) * _m2;                                                \
    P##r1 += (x1) * (x1) * _m2;                                                \
    P##r2 += (x2) * (x2) * _m2;                                                \
  }

#define SEM_OUT(P, koff)                                                       \
  {                                                                            \
    float st0 = P##n, st1 = P##n2, st2 = P##p0, st3 = P##p1, st4 = P##p2,      \
          st5 = P##q0, st6 = P##q1, st7 = P##q2, st8 = P##r0, st9 = P##r1,     \
          st10 = P##r2;                                                        \
    float* dst = ws + 51 + (size_t)((b * 8 + (koff)) * 11);                    \
    st0 = wave_reduce(st0);   if (lane == 0) atomicAdd(&dst[0], st0);          \
    st1 = wave_reduce(st1);   if (lane == 0) atomicAdd(&dst[1], st1);          \
    st2 = wave_reduce(st2);   if (lane == 0) atomicAdd(&dst[2], st2);          \
    st3 = wave_reduce(st3);   if (lane == 0) atomicAdd(&dst[3], st3);          \
    st4 = wave_reduce(st4);   if (lane == 0) atomicAdd(&dst[4], st4);          \
    st5 = wave_reduce(st5);   if (lane == 0) atomicAdd(&dst[5], st5);          \
    st6 = wave_reduce(st6);   if (lane == 0) atomicAdd(&dst[6], st6);          \
    st7 = wave_reduce(st7);   if (lane == 0) atomicAdd(&dst[7], st7);          \
    st8 = wave_reduce(st8);   if (lane == 0) atomicAdd(&dst[8], st8);          \
    st9 = wave_reduce(st9);   if (lane == 0) atomicAdd(&dst[9], st9);          \
    st10 = wave_reduce(st10); if (lane == 0) atomicAdd(&dst[10], st10);        \
  }

__global__ __launch_bounds__(256) void mega_kernel(
    const float* __restrict__ L, const float* __restrict__ R,
    const float* __restrict__ I, const float* __restrict__ M,
    float* __restrict__ ws) {
  const int bid = blockIdx.x;
  const int tid = threadIdx.x;
  const int lane = tid & 63;

  if (bid < SEM_BLOCKS) {
    // ---------------- semantic stats: R (B,3,H,W) x M (B,8,H,W) ------------
    const int b = bid >> 7;      // 0..15
    const int xb = bid & 127;    // 0..127
    const int wv = tid >> 6;     // 0..3
    const int k0 = wv * 2;       // k pair {k0, k0+1}
    const float4* R4 = (const float4*)(R + (size_t)b * 3 * HW);
    const float4* M4 = (const float4*)(M + (size_t)b * 8 * HW);
    SEM_ACC(A)
    SEM_ACC(Bk)
    int i = xb * 64 + lane;      // 0..8191
#pragma unroll 1
    for (int it = 0; it < 8; ++it, i += 8192) {
      float4 r0 = R4[i];
      float4 r1 = R4[i + HW4];
      float4 r2 = R4[i + 2 * HW4];
      float4 ma = M4[i + k0 * HW4];
      float4 mb = M4[i + k0 * HW4 + HW4];
      SEM_DO(A, ma.x, r0.x, r1.x, r2.x)
      SEM_DO(A, ma.y, r0.y, r1.y, r2.y)
      SEM_DO(A, ma.z, r0.z, r1.z, r2.z)
      SEM_DO(A, ma.w, r0.w, r1.w, r2.w)
      SEM_DO(Bk, mb.x, r0.x, r1.x, r2.x)
      SEM_DO(Bk, mb.y, r0.y, r1.y, r2.y)
      SEM_DO(Bk, mb.z, r0.z, r1.z, r2.z)
      SEM_DO(Bk, mb.w, r0.w, r1.w, r2.w)
    }
    SEM_OUT(A, k0)
    SEM_OUT(Bk, k0 + 1)
    return;
  }

  if (bid < SEM_BLOCKS + L_BLOCKS) {
    // ---------------- L band: TV (v+h) + exposure patches ------------------
    // One block = 16-row band of one image. Thread (half, c4) streams rows
    // half*8 .. half*8+7 at float4-column c4 (perfectly coalesced per row).
    const int band = bid - SEM_BLOCKS;
    const int b = band >> 5;     // 0..15
    const int pr = band & 31;    // patch row 0..31
    const int half = tid >> 7;   // 0..1
    const int c4 = tid & 127;    // f4 column 0..127
    const int row0 = pr * 16 + half * 8;
    const float* Lb = L + (size_t)b * HW;
    const float4* L4b = (const float4*)Lb;
    __shared__ float part[2][128];
    __shared__ float redv[4], redh[4];

    float sv = 0.f, sh = 0.f, ps = 0.f;
    float4 cur = L4b[row0 * 128 + c4];
#pragma unroll
    for (int r = 0; r < 8; ++r) {
      sh += fabsf(cur.x - cur.y) + fabsf(cur.y - cur.z) + fabsf(cur.z - cur.w);
      if (c4 < 127) sh += fabsf(cur.w - Lb[(row0 + r) * 512 + c4 * 4 + 4]);
      ps += (cur.x + cur.y) + (cur.z + cur.w);
      int nr = row0 + r + 1;
      if (nr < 512) {
        float4 nxt = L4b[nr * 128 + c4];
        sv += fabsf(cur.x - nxt.x) + fabsf(cur.y - nxt.y) +
              fabsf(cur.z - nxt.z) + fabsf(cur.w - nxt.w);
        cur = nxt;
      }
    }
    part[half][c4] = ps;
    sv = wave_reduce(sv);
    sh = wave_reduce(sh);
    int wv = tid >> 6;
    if (lane == 0) { redv[wv] = sv; redh[wv] = sh; }
    __syncthreads();
    if (tid == 0) {
      atomicAdd(&ws[1], (redv[0] + redv[1]) + (redv[2] + redv[3]));
      atomicAdd(&ws[2], (redh[0] + redh[1]) + (redh[2] + redh[3]));
    }
    float e = 0.f;
    if (tid < 32) {  // patch p = tid covers f4 cols [4p, 4p+4)
      float s = 0.f;
#pragma unroll
      for (int h = 0; h < 2; ++h)
#pragma unroll
        for (int q = 0; q < 4; ++q) s += part[h][tid * 4 + q];
      float d = s * (1.0f / 256.0f) - 0.6f;
      e = d * d;
    }
    e = wave_reduce(e);  // waves 1..3 reduce zeros, harmless
    if (tid == 0) atomicAdd(&ws[0], e);
    return;
  }

  {
    // ---------------- color: per (b,c) channel sums of I_enh ---------------
    const int cid = bid - (SEM_BLOCKS + L_BLOCKS);
    const int slice = cid >> 4;  // 0..47
    const int xb = cid & 15;
    const float4* I4 = (const float4*)(I + (size_t)slice * HW);
    float s = 0.f;
    int i = xb * 256 + tid;
#pragma unroll 4
    for (int it = 0; it < 16; ++it, i += 4096) {
      float4 v = I4[i];
      s += (v.x + v.y) + (v.z + v.w);
    }
    s = wave_reduce(s);
    __shared__ float red[4];
    int wv = tid >> 6;
    if (lane == 0) red[wv] = s;
    __syncthreads();
    if (tid == 0)
      atomicAdd(&ws[3 + slice], (red[0] + red[1]) + (red[2] + red[3]));
  }
}

// ---------------- final combine ----------------
__global__ __launch_bounds__(256) void final_kernel(const float* __restrict__ ws,
                                                    float* __restrict__ out) {
  __shared__ float red[256];
  int t = threadIdx.x;
  float sem = 0.f;
  if (t < 128) {
    const float* s = ws + 51 + t * 11;
    float n = s[0] + 1e-6f;
    float v = 0.f;
#pragma unroll
    for (int c = 0; c < 3; ++c) {
      float mean = s[2 + c] / n;
      v += s[8 + c] - 2.0f * mean * s[5 + c] + mean * mean * s[1];
    }
    sem = v / n;
  }
  red[t] = sem;
  __syncthreads();
  for (int s = 128; s > 0; s >>= 1) {
    if (t < s) red[t] += red[t + s];
    __syncthreads();
  }
  if (t == 0) {
    float L_sem = red[0] / 16.0f;
    float L_exp = ws[0] / (float)NPATCH;
    float L_tv = ws[1] / (16.0f * 511.0f * 512.0f) +
                 ws[2] / (16.0f * 512.0f * 511.0f);
    float L_color = 0.f;
#pragma unroll
    for (int b = 0; b < 16; ++b) {
      float r = ws[3 + b * 3 + 0] * (1.0f / (float)HW);
      float g = ws[3 + b * 3 + 1] * (1.0f / (float)HW);
      float bl = ws[3 + b * 3 + 2] * (1.0f / (float)HW);
      L_color += (r - g) * (r - g) + (r - bl) * (r - bl) + (g - bl) * (g - bl);
    }
    L_color *= (1.0f / 16.0f);
    out[0] = 10.0f * L_exp + 1.0f * L_tv + 10.0f * L_color + 50.0f * L_sem;
  }
}

extern "C" void kernel_launch(void* const* d_in, const int* in_sizes, int n_in,
                              void* d_out, int out_size, void* d_ws, size_t ws_size,
                              hipStream_t stream) {
  const float* L     = (const float*)d_in[0];  // (16,1,512,512)
  const float* R     = (const float*)d_in[1];  // (16,3,512,512)
  const float* I_enh = (const float*)d_in[2];  // (16,3,512,512)
  const float* M     = (const float*)d_in[3];  // (16,8,512,512)
  float* out = (float*)d_out;
  float* ws  = (float*)d_ws;

  hipMemsetAsync(d_ws, 0, WS_FLOATS * sizeof(float), stream);
  mega_kernel<<<TOTAL_BLOCKS, 256, 0, stream>>>(L, R, I_enh, M, ws);
  final_kernel<<<1, 256, 0, stream>>>(ws, out);
}